// Round 5
// baseline (73.006 us; speedup 1.0000x reference)
//
#include <hip/hip_runtime.h>
#include <hip/hip_bf16.h>

#define H_ 200
#define W_ 200
#define HW_ 40000
#define C_ 256
#define B_ 2
#define P_ 12
#define NBINS 144
#define CHUNK 32
#define TP 65   // staging tile pitch (floats)

typedef float f32x4 __attribute__((ext_vector_type(4)));

// RNE float -> bf16 bits (normal inputs; matches __float2bfloat16)
__device__ __forceinline__ unsigned int bfbits(float f) {
  unsigned int u = __float_as_uint(f);
  return (u + 0x7FFFu + ((u >> 16) & 1u)) >> 16;
}
__device__ __forceinline__ float blo(unsigned int u) {
  return __uint_as_float(u << 16);
}
__device__ __forceinline__ float bhi(unsigned int u) {
  return __uint_as_float(u & 0xFFFF0000u);
}
__device__ __forceinline__ void nt_store4(float* p, float a, float b, float c,
                                          float d) {
  f32x4 v = {a, b, c, d};
  __builtin_nontemporal_store(v, reinterpret_cast<f32x4*>(p));
}

// ---------------- Kernel 1: NCHW fp32 -> NHWC bf16 ----------------
__global__ __launch_bounds__(256) void transpose_to_bf16_nhwc(
    const float* __restrict__ x, __hip_bfloat16* __restrict__ feat) {
  __shared__ float sT[64 * TP];
  const int t = threadIdx.x;
  const int p0 = blockIdx.x * 64;   // 625 tiles
  const int c0 = blockIdx.y * 64;   // 4 tiles
  const int b = blockIdx.z;

  const int px4 = (t & 15) * 4;
  const int cl = t >> 4;  // 0..15
#pragma unroll
  for (int pass = 0; pass < 4; ++pass) {
    const int c = pass * 16 + cl;   // 0..63
    const f32x4 v = __builtin_nontemporal_load(reinterpret_cast<const f32x4*>(
        x + (size_t)(b * C_ + c0 + c) * HW_ + p0 + px4));
    sT[(px4 + 0) * TP + c] = v.x;
    sT[(px4 + 1) * TP + c] = v.y;
    sT[(px4 + 2) * TP + c] = v.z;
    sT[(px4 + 3) * TP + c] = v.w;
  }
  __syncthreads();
  const int c8 = (t & 7) * 8;
  const int pxs = t >> 3;  // 0..31
#pragma unroll
  for (int pass = 0; pass < 2; ++pass) {
    const int px = pass * 32 + pxs;
    const float* r = &sT[px * TP + c8];
    uint4 w;
    w.x = bfbits(r[0]) | (bfbits(r[1]) << 16);
    w.y = bfbits(r[2]) | (bfbits(r[3]) << 16);
    w.z = bfbits(r[4]) | (bfbits(r[5]) << 16);
    w.w = bfbits(r[6]) | (bfbits(r[7]) << 16);
    *reinterpret_cast<uint4*>(feat + (size_t)(b * HW_ + p0 + px) * C_ + c0 +
                              c8) = w;
  }
}

// ---------------- Kernel 2: gather + blend, reg-prefetch pipeline ----------
// Grid (4 c-tiles, N). Block 256 = 32 bin-slots x 8 lanes (8 ch, 16 B loads;
// each corner = one full 128 B line read by 8 lanes). Depth-1 register
// prefetch: chunk ch+1's 4 corner loads are issued before blending chunk ch,
// hiding L2/LLC miss latency under blend + barrier + nt-store.
__global__ __launch_bounds__(256, 4) void roi_gather_bf16(
    const __hip_bfloat16* __restrict__ feat, const float* __restrict__ rois,
    float* __restrict__ out, int N) {
  __shared__ float sw0[NBINS], sw1[NBINS], sw2[NBINS], sw3[NBINS];
  __shared__ int so0[NBINS], so1[NBINS], so2[NBINS], so3[NBINS];
  __shared__ float tile[2][CHUNK * TP];

  const int t = threadIdx.x;
  const int n = blockIdx.y;
  const int cbase = blockIdx.x * 64;
  if (n >= N) return;

  if (t < NBINS) {
    const int py = t / P_;
    const int px = t - py * P_;
    const float rx1 = rois[n * 5 + 1] * 0.25f;
    const float ry1 = rois[n * 5 + 2] * 0.25f;
    const float rx2 = rois[n * 5 + 3] * 0.25f;
    const float ry2 = rois[n * 5 + 4] * 0.25f;
    const int bi = (int)rois[n * 5 + 0];
    const float bh = (ry2 - ry1) * (1.0f / P_);
    const float bw = (rx2 - rx1) * (1.0f / P_);
    float ys = ry1 + ((float)py + 0.5f) * bh;
    float xs = rx1 + ((float)px + 0.5f) * bw;
    ys = fminf(fmaxf(ys, 0.0f), (float)(H_ - 1));
    xs = fminf(fmaxf(xs, 0.0f), (float)(W_ - 1));
    const float y0f = floorf(ys);
    const float x0f = floorf(xs);
    const float ly = ys - y0f;
    const float lx = xs - x0f;
    const int y0 = (int)y0f;
    const int x0 = (int)x0f;
    const int y1 = min(y0 + 1, H_ - 1);
    const int x1 = min(x0 + 1, W_ - 1);
    sw0[t] = (1.0f - ly) * (1.0f - lx);
    sw1[t] = (1.0f - ly) * lx;
    sw2[t] = ly * (1.0f - lx);
    sw3[t] = ly * lx;
    const int pb = bi * HW_;
    so0[t] = (pb + y0 * W_ + x0) * C_;
    so1[t] = (pb + y0 * W_ + x1) * C_;
    so2[t] = (pb + y1 * W_ + x0) * C_;
    so3[t] = (pb + y1 * W_ + x1) * C_;
  }
  __syncthreads();

  const int binq = t >> 3;        // 0..31: bin slot in chunk
  const int c8 = (t & 7) * 8;     // channel base within 64-ch tile (8 bf16)
  const __hip_bfloat16* fb = feat + cbase;
  float* outn = out + ((size_t)n * C_ + cbase) * NBINS;

  uint4 a0 = {0, 0, 0, 0}, b0 = a0, c0 = a0, d0 = a0;
  uint4 a1 = a0, b1 = a0, c1 = a0, d1 = a0;

  // prologue: chunk 0 loads (all 32 bin slots valid)
  {
    const int bin = binq;
    a0 = *reinterpret_cast<const uint4*>(fb + so0[bin] + c8);
    b0 = *reinterpret_cast<const uint4*>(fb + so1[bin] + c8);
    c0 = *reinterpret_cast<const uint4*>(fb + so2[bin] + c8);
    d0 = *reinterpret_cast<const uint4*>(fb + so3[bin] + c8);
  }

  for (int ch = 0; ch < 5; ++ch) {
    const int cs = (ch == 4) ? 16 : CHUNK;
    // prefetch chunk ch+1 (guarded: last chunk has only 16 bins)
    if (ch + 1 < 5) {
      const int ns = (ch + 1 == 4) ? 16 : CHUNK;
      if (binq < ns) {
        const int bin = (ch + 1) * CHUNK + binq;
        a1 = *reinterpret_cast<const uint4*>(fb + so0[bin] + c8);
        b1 = *reinterpret_cast<const uint4*>(fb + so1[bin] + c8);
        c1 = *reinterpret_cast<const uint4*>(fb + so2[bin] + c8);
        d1 = *reinterpret_cast<const uint4*>(fb + so3[bin] + c8);
      }
    }
    float* tb = tile[ch & 1];
    if (binq < cs) {
      const int bin = ch * CHUNK + binq;
      const float w0 = sw0[bin], w1 = sw1[bin], w2 = sw2[bin], w3 = sw3[bin];
      float* tp = tb + binq * TP + c8;
      tp[0] = w0 * blo(a0.x) + w1 * blo(b0.x) + w2 * blo(c0.x) + w3 * blo(d0.x);
      tp[1] = w0 * bhi(a0.x) + w1 * bhi(b0.x) + w2 * bhi(c0.x) + w3 * bhi(d0.x);
      tp[2] = w0 * blo(a0.y) + w1 * blo(b0.y) + w2 * blo(c0.y) + w3 * blo(d0.y);
      tp[3] = w0 * bhi(a0.y) + w1 * bhi(b0.y) + w2 * bhi(c0.y) + w3 * bhi(d0.y);
      tp[4] = w0 * blo(a0.z) + w1 * blo(b0.z) + w2 * blo(c0.z) + w3 * blo(d0.z);
      tp[5] = w0 * bhi(a0.z) + w1 * bhi(b0.z) + w2 * bhi(c0.z) + w3 * bhi(d0.z);
      tp[6] = w0 * blo(a0.w) + w1 * blo(b0.w) + w2 * blo(c0.w) + w3 * blo(d0.w);
      tp[7] = w0 * bhi(a0.w) + w1 * bhi(b0.w) + w2 * bhi(c0.w) + w3 * bhi(d0.w);
    }
    __syncthreads();
    if (cs == CHUNK) {
#pragma unroll
      for (int r = 0; r < 2; ++r) {
        const int s = r * 256 + t;   // 0..511
        const int cc = s >> 3;       // channel 0..63
        const int q = s & 7;         // bin-quad 0..7
        const float* tr = tb + cc;
        nt_store4(outn + (size_t)cc * NBINS + ch * CHUNK + 4 * q,
                  tr[(4 * q + 0) * TP], tr[(4 * q + 1) * TP],
                  tr[(4 * q + 2) * TP], tr[(4 * q + 3) * TP]);
      }
    } else {
      const int cc = t >> 2;         // channel 0..63
      const int q = t & 3;           // bin-quad 0..3
      const float* tr = tb + cc;
      nt_store4(outn + (size_t)cc * NBINS + ch * CHUNK + 4 * q,
                tr[(4 * q + 0) * TP], tr[(4 * q + 1) * TP],
                tr[(4 * q + 2) * TP], tr[(4 * q + 3) * TP]);
    }
    a0 = a1; b0 = b1; c0 = c1; d0 = d1;
  }
}

// ---------------- Fallback: naive NCHW gather (safety only) ----------------
__global__ void roi_naive_nchw(const float* __restrict__ x,
                               const float* __restrict__ rois,
                               float* __restrict__ out, int total) {
  const int gid = blockIdx.x * blockDim.x + threadIdx.x;
  if (gid >= total) return;
  const int bin = gid % NBINS;
  const int c   = (gid / NBINS) % C_;
  const int n   = gid / (NBINS * C_);
  const int py  = bin / P_;
  const int px  = bin - py * P_;
  const float rx1 = rois[n * 5 + 1] * 0.25f;
  const float ry1 = rois[n * 5 + 2] * 0.25f;
  const float rx2 = rois[n * 5 + 3] * 0.25f;
  const float ry2 = rois[n * 5 + 4] * 0.25f;
  const int bi = (int)rois[n * 5 + 0];
  const float bh = (ry2 - ry1) * (1.0f / P_);
  const float bw = (rx2 - rx1) * (1.0f / P_);
  float ys = fminf(fmaxf(ry1 + ((float)py + 0.5f) * bh, 0.0f), (float)(H_ - 1));
  float xs = fminf(fmaxf(rx1 + ((float)px + 0.5f) * bw, 0.0f), (float)(W_ - 1));
  const float y0f = floorf(ys), x0f = floorf(xs);
  const float ly = ys - y0f, lx = xs - x0f;
  const int y0 = (int)y0f, x0 = (int)x0f;
  const int y1 = min(y0 + 1, H_ - 1), x1 = min(x0 + 1, W_ - 1);
  const float* p = x + (size_t)(bi * C_ + c) * HW_;
  const float v = (1.0f - ly) * (1.0f - lx) * p[y0 * W_ + x0] +
                  (1.0f - ly) * lx * p[y0 * W_ + x1] +
                  ly * (1.0f - lx) * p[y1 * W_ + x0] +
                  ly * lx * p[y1 * W_ + x1];
  out[gid] = v;
}

extern "C" void kernel_launch(void* const* d_in, const int* in_sizes, int n_in,
                              void* d_out, int out_size, void* d_ws,
                              size_t ws_size, hipStream_t stream) {
  const float* x    = (const float*)d_in[0];
  const float* rois = (const float*)d_in[1];
  float* out = (float*)d_out;
  const int N = in_sizes[1] / 5;

  const size_t need = (size_t)B_ * C_ * HW_ * sizeof(__hip_bfloat16);
  if (ws_size >= need) {
    __hip_bfloat16* feat = (__hip_bfloat16*)d_ws;
    transpose_to_bf16_nhwc<<<dim3(HW_ / 64, C_ / 64, B_), 256, 0, stream>>>(
        x, feat);
    roi_gather_bf16<<<dim3(C_ / 64, N), 256, 0, stream>>>(feat, rois, out, N);
  } else {
    const int total = N * C_ * NBINS;
    roi_naive_nchw<<<dim3((total + 255) / 256), 256, 0, stream>>>(x, rois, out,
                                                                  total);
  }
}